// Round 1
// baseline (263.411 us; speedup 1.0000x reference)
//
#include <hip/hip_runtime.h>
#include <hip/hip_bf16.h>

// DeepViT re-attention, fused flash-style two-pass.
// Pipeline:
//  k0 convert3 : x, w_qkv, w_out fp32 -> bf16 (ws)
//  k1 gemm<1>  : qkv = x @ w_qkv^T (bf16 MFMA); epilogue scatters to
//                q[b,h,n,d]*scale*log2e, k[b,h,n,d], vT[b,h,d,n]  (all bf16)
//  k2 passA    : per (b,h,i): online max/denominator of softmax (exp2 domain)
//  k3 passB    : recompute S', p=exp2(S'-m)/l, 8x8 head mix + LN over heads
//                (in-lane), PV accumulate -> inner[b,n,512] bf16
//  k4 gemm<0>  : out = inner @ w_out^T + b_out  (fp32 out)

typedef __attribute__((ext_vector_type(8))) short bfx8;
typedef __attribute__((ext_vector_type(4))) float f32x4;
typedef unsigned short u16;

#define QSCALE 0.18033688011112042f  /* (1/8) * log2(e) */

static __device__ inline u16 f2bf(float f) {
  union { float f; unsigned u; } cv; cv.f = f;
  unsigned u = cv.u;
  u += 0x7fffu + ((u >> 16) & 1u);   // RNE
  return (u16)(u >> 16);
}

// ---------------- k0: fp32 -> bf16 converts ----------------
// X: 2097152, WQ: 786432, WO: 262144 elems; 4 elems/thread; grid 3072x256.
__global__ __launch_bounds__(256) void convert3(
    const float* __restrict__ x, const float* __restrict__ wq,
    const float* __restrict__ wo,
    u16* __restrict__ xb, u16* __restrict__ wqb, u16* __restrict__ wob) {
  int e = (blockIdx.x * 256 + threadIdx.x) * 4;
  const float* src; u16* dst; int off;
  if (e < 2097152)      { src = x;  dst = xb;  off = e; }
  else if (e < 2883584) { src = wq; dst = wqb; off = e - 2097152; }
  else                  { src = wo; dst = wob; off = e - 2883584; }
  float4 v = *(const float4*)&src[off];
  ushort4 o; o.x = f2bf(v.x); o.y = f2bf(v.y); o.z = f2bf(v.z); o.w = f2bf(v.w);
  *(ushort4*)&dst[off] = o;
}

// ---------------- k1/k4: bf16 GEMM, C = A @ B^T ----------------
// A [M,512] row-major bf16, B [N,512] row-major bf16 (i.e. already B^T).
// 128x128 tile, BK=32, 256 thr (4 waves, 2x2 of 64x64 each).
// EPI=0: out fp32 + bias. EPI=1: scatter to q (scaled) / k / vT bf16.
template<int EPI>
__global__ __launch_bounds__(256) void gemm_k(
    const u16* __restrict__ A, const u16* __restrict__ B, int K,
    float* __restrict__ outf, const float* __restrict__ bias,
    u16* __restrict__ qb, u16* __restrict__ kb, u16* __restrict__ vtb) {
  __shared__ u16 As[128 * 32];
  __shared__ u16 Bs[128 * 32];
  const int t = threadIdx.x, lane = t & 63;
  const int wm = (t >> 6) >> 1, wn = (t >> 6) & 1;
  const int m0 = blockIdx.y * 128, n0 = blockIdx.x * 128;
  const int li = lane & 15, lg = lane >> 4;
  const int rowA = t >> 2, kb8 = (t & 3) * 8;   // 16B per thread, 4 thr/row
  f32x4 acc[4][4] = {};
  for (int k0 = 0; k0 < K; k0 += 32) {
    __syncthreads();
    *(bfx8*)&As[rowA * 32 + kb8]        = *(const bfx8*)&A[(size_t)(m0 + rowA) * K + k0 + kb8];
    *(bfx8*)&As[(rowA + 64) * 32 + kb8] = *(const bfx8*)&A[(size_t)(m0 + rowA + 64) * K + k0 + kb8];
    *(bfx8*)&Bs[rowA * 32 + kb8]        = *(const bfx8*)&B[(size_t)(n0 + rowA) * K + k0 + kb8];
    *(bfx8*)&Bs[(rowA + 64) * 32 + kb8] = *(const bfx8*)&B[(size_t)(n0 + rowA + 64) * K + k0 + kb8];
    __syncthreads();
    bfx8 af[4], bf_[4];
#pragma unroll
    for (int mi = 0; mi < 4; mi++)
      af[mi] = *(const bfx8*)&As[(wm * 64 + mi * 16 + li) * 32 + lg * 8];
#pragma unroll
    for (int ni = 0; ni < 4; ni++)
      bf_[ni] = *(const bfx8*)&Bs[(wn * 64 + ni * 16 + li) * 32 + lg * 8];
#pragma unroll
    for (int mi = 0; mi < 4; mi++)
#pragma unroll
      for (int ni = 0; ni < 4; ni++)
        acc[mi][ni] = __builtin_amdgcn_mfma_f32_16x16x32_bf16(af[mi], bf_[ni], acc[mi][ni], 0, 0, 0);
  }
  // epilogue: C row = m0+wm*64+mi*16+lg*4+r, col = n0+wn*64+ni*16+li
#pragma unroll
  for (int mi = 0; mi < 4; mi++) {
#pragma unroll
    for (int ni = 0; ni < 4; ni++) {
      const int nc  = n0 + wn * 64 + ni * 16 + li;
      const int mrb = m0 + wm * 64 + mi * 16 + lg * 4;
      if (EPI == 0) {
        const float bv = bias[nc];
#pragma unroll
        for (int r = 0; r < 4; r++)
          outf[(size_t)(mrb + r) * 512 + nc] = acc[mi][ni][r] + bv;
      } else {
        const int part = nc >> 9, within = nc & 511;
        const int h = within >> 6, d = within & 63;
        const int bb = mrb >> 11, ii = mrb & 2047;
        if (part == 0) {
#pragma unroll
          for (int r = 0; r < 4; r++)
            qb[(((size_t)bb * 8 + h) * 2048 + ii + r) * 64 + d] = f2bf(acc[mi][ni][r] * QSCALE);
        } else if (part == 1) {
#pragma unroll
          for (int r = 0; r < 4; r++)
            kb[(((size_t)bb * 8 + h) * 2048 + ii + r) * 64 + d] = f2bf(acc[mi][ni][r]);
        } else {
          ushort4 u;
          u.x = f2bf(acc[mi][ni][0]); u.y = f2bf(acc[mi][ni][1]);
          u.z = f2bf(acc[mi][ni][2]); u.w = f2bf(acc[mi][ni][3]);
          *(ushort4*)&vtb[(((size_t)bb * 8 + h) * 64 + d) * 2048 + ii] = u;
        }
      }
    }
  }
}

// ---------------- k2: softmax stats (m, 1/l) in exp2 domain ----------------
// grid (32, 16): x = i-tile-of-64, y = b*8+h. 4 waves, wave w -> i-tile of 16.
// S'^T = mfma(K, Q): lane holds S'[j=j0+lg*4+r][i=i0+li] -> per-lane online
// (m,l) over its own j-subset, no shuffles in loop; combine 4 partials at end.
__global__ __launch_bounds__(256) void passA(
    const u16* __restrict__ qb, const u16* __restrict__ kb,
    float2* __restrict__ stats) {
  const int t = threadIdx.x, lane = t & 63, w = t >> 6;
  const int bh = blockIdx.y;
  const int i0 = blockIdx.x * 64 + w * 16;
  const int li = lane & 15, lg = lane >> 4;
  const u16* Qh = qb + ((size_t)bh * 2048 + i0 + li) * 64;
  const u16* Kb = kb + (size_t)bh * 2048 * 64;
  const bfx8 q0 = *(const bfx8*)&Qh[lg * 8];
  const bfx8 q1 = *(const bfx8*)&Qh[32 + lg * 8];
  float m = -1e30f, l = 0.f;
  for (int j0 = 0; j0 < 2048; j0 += 16) {
    const u16* Kh = Kb + (size_t)(j0 + li) * 64;
    bfx8 k0 = *(const bfx8*)&Kh[lg * 8];
    bfx8 k1 = *(const bfx8*)&Kh[32 + lg * 8];
    f32x4 s = {0.f, 0.f, 0.f, 0.f};
    s = __builtin_amdgcn_mfma_f32_16x16x32_bf16(k0, q0, s, 0, 0, 0);
    s = __builtin_amdgcn_mfma_f32_16x16x32_bf16(k1, q1, s, 0, 0, 0);
    float mt = fmaxf(fmaxf(s[0], s[1]), fmaxf(s[2], s[3]));
    float mn = fmaxf(m, mt);
    l = fmaf(l, exp2f(m - mn),
             exp2f(s[0] - mn) + exp2f(s[1] - mn) + exp2f(s[2] - mn) + exp2f(s[3] - mn));
    m = mn;
  }
  for (int off = 16; off < 64; off <<= 1) {
    float mo = __shfl_xor(m, off, 64);
    float lo = __shfl_xor(l, off, 64);
    float mn = fmaxf(m, mo);
    l = l * exp2f(m - mn) + lo * exp2f(mo - mn);
    m = mn;
  }
  if (lane < 16) stats[(size_t)bh * 2048 + i0 + li] = make_float2(m, 1.f / l);
}

// ---------------- k3: pass B — normalize, head-mix, LN, PV ----------------
// grid (128, 2): x = i-tile-of-16, y = b. 512 thr = 8 waves.
// Phase 1 (wave w = j-slab jm+w*16): S'^T for ALL 8 heads -> p in-lane ->
//   8x8 mix + LN over heads -> A'' bf16 to LDS (XOR-swizzled).
// Phase 2 (wave w = head w): PV MFMAs over the 128-j macro tile.
__global__ __launch_bounds__(512) void passB(
    const u16* __restrict__ qb, const u16* __restrict__ kb,
    const u16* __restrict__ vtb, const float2* __restrict__ stats,
    const float* __restrict__ Wmix, const float* __restrict__ lng,
    const float* __restrict__ lnb, u16* __restrict__ inner) {
  __shared__ u16 A2[8 * 16 * 128];  // [g][i][j] bf16, j XOR-swizzled by i
  const int t = threadIdx.x, lane = t & 63, w = t >> 6;
  const int b = blockIdx.y, i0 = blockIdx.x * 16;
  const int li = lane & 15, lg = lane >> 4;
  const int swz = (li & 7) << 3;

  float wm_[8][8], lng_[8], lnb_[8];
#pragma unroll
  for (int h = 0; h < 8; h++)
#pragma unroll
    for (int g = 0; g < 8; g++) wm_[h][g] = Wmix[h * 8 + g];
#pragma unroll
  for (int g = 0; g < 8; g++) { lng_[g] = lng[g]; lnb_[g] = lnb[g]; }

  bfx8 qf[8][2];
  float2 st[8];
#pragma unroll
  for (int h = 0; h < 8; h++) {
    const u16* Qh = qb + (((size_t)(b * 8 + h)) * 2048 + i0 + li) * 64;
    qf[h][0] = *(const bfx8*)&Qh[lg * 8];
    qf[h][1] = *(const bfx8*)&Qh[32 + lg * 8];
    st[h] = stats[((size_t)(b * 8 + h)) * 2048 + i0 + li];
  }
  f32x4 pacc[4] = {};
  for (int jm = 0; jm < 2048; jm += 128) {
    const int j0 = jm + w * 16;
    float p[8][4];
#pragma unroll
    for (int h = 0; h < 8; h++) {
      const u16* Kh = kb + (((size_t)(b * 8 + h)) * 2048 + j0 + li) * 64;
      bfx8 k0 = *(const bfx8*)&Kh[lg * 8];
      bfx8 k1 = *(const bfx8*)&Kh[32 + lg * 8];
      f32x4 s = {0.f, 0.f, 0.f, 0.f};
      s = __builtin_amdgcn_mfma_f32_16x16x32_bf16(k0, qf[h][0], s, 0, 0, 0);
      s = __builtin_amdgcn_mfma_f32_16x16x32_bf16(k1, qf[h][1], s, 0, 0, 0);
#pragma unroll
      for (int r = 0; r < 4; r++) p[h][r] = exp2f(s[r] - st[h].x) * st[h].y;
    }
    float av[8][4];
#pragma unroll
    for (int r = 0; r < 4; r++) {
      float a_[8]; float sum = 0.f, sumsq = 0.f;
#pragma unroll
      for (int g = 0; g < 8; g++) {
        float acc = 0.f;
#pragma unroll
        for (int h = 0; h < 8; h++) acc = fmaf(p[h][r], wm_[h][g], acc);
        a_[g] = acc; sum += acc; sumsq = fmaf(acc, acc, sumsq);
      }
      const float mu = sum * 0.125f;
      const float var = fmaf(sumsq, 0.125f, -mu * mu);
      const float rs = rsqrtf(var + 1e-5f);
#pragma unroll
      for (int g = 0; g < 8; g++)
        av[g][r] = fmaf((a_[g] - mu) * rs, lng_[g], lnb_[g]);
    }
    {
      const int jsw = (w * 16 + lg * 4) ^ swz;   // 4 consecutive j per lane
#pragma unroll
      for (int g = 0; g < 8; g++) {
        ushort4 u;
        u.x = f2bf(av[g][0]); u.y = f2bf(av[g][1]);
        u.z = f2bf(av[g][2]); u.w = f2bf(av[g][3]);
        *(ushort4*)&A2[(g * 16 + li) * 128 + jsw] = u;
      }
    }
    __syncthreads();
    {
      const u16* Vh = vtb + ((size_t)(b * 8 + w)) * 64 * 2048;
#pragma unroll
      for (int kc = 0; kc < 4; kc++) {
        const int jr = (kc * 32 + lg * 8) ^ swz;
        bfx8 af = *(const bfx8*)&A2[(w * 16 + li) * 128 + jr];
#pragma unroll
        for (int nd = 0; nd < 4; nd++) {
          bfx8 vf = *(const bfx8*)&Vh[(size_t)(nd * 16 + li) * 2048 + jm + kc * 32 + lg * 8];
          pacc[nd] = __builtin_amdgcn_mfma_f32_16x16x32_bf16(af, vf, pacc[nd], 0, 0, 0);
        }
      }
    }
    __syncthreads();
  }
#pragma unroll
  for (int nd = 0; nd < 4; nd++)
#pragma unroll
    for (int r = 0; r < 4; r++)
      inner[((size_t)b * 2048 + i0 + lg * 4 + r) * 512 + w * 64 + nd * 16 + li] =
          f2bf(pacc[nd][r]);
}

// ---------------- host ----------------
extern "C" void kernel_launch(void* const* d_in, const int* in_sizes, int n_in,
                              void* d_out, int out_size, void* d_ws, size_t ws_size,
                              hipStream_t stream) {
  const float* x      = (const float*)d_in[0];
  const float* w_qkv  = (const float*)d_in[1];
  const float* reattn = (const float*)d_in[2];
  const float* ln_g   = (const float*)d_in[3];
  const float* ln_b   = (const float*)d_in[4];
  const float* w_out  = (const float*)d_in[5];
  const float* b_out  = (const float*)d_in[6];
  float* out = (float*)d_out;
  char* ws = (char*)d_ws;
  // ws layout (bytes): all 256-aligned, total ~23.3 MB
  u16*    xb    = (u16*)(ws + 0);          // 4096x512 bf16
  u16*    wqb   = (u16*)(ws + 4194304);    // 1536x512 bf16
  u16*    wob   = (u16*)(ws + 5767168);    // 512x512 bf16
  u16*    qbf   = (u16*)(ws + 6291456);    // [2,8,2048,64] bf16 (scaled)
  u16*    kbf   = (u16*)(ws + 10485760);   // [2,8,2048,64] bf16
  u16*    vtb   = (u16*)(ws + 14680064);   // [2,8,64,2048] bf16
  float2* stats = (float2*)(ws + 18874368);// [2,8,2048] (m, 1/l)
  u16*    inner = (u16*)(ws + 19136512);   // 4096x512 bf16

  convert3<<<3072, 256, 0, stream>>>(x, w_qkv, w_out, xb, wqb, wob);
  gemm_k<1><<<dim3(12, 32), 256, 0, stream>>>(xb, wqb, 512, nullptr, nullptr, qbf, kbf, vtb);
  passA<<<dim3(32, 16), 256, 0, stream>>>(qbf, kbf, stats);
  passB<<<dim3(128, 2), 512, 0, stream>>>(qbf, kbf, vtb, stats, reattn, ln_g, ln_b, inner);
  gemm_k<0><<<dim3(4, 32), 256, 0, stream>>>(inner, wob, 512, out, b_out, nullptr, nullptr, nullptr);
}